// Round 1
// baseline (707.872 us; speedup 1.0000x reference)
//
#include <hip/hip_runtime.h>
#include <hip/hip_bf16.h>
#include <stdint.h>

// Problem constants (MixtureOfLinear: B=4,S=2048,D=4096, E=8, top-2, rank 16)
#define T_TOKENS 8192
#define DIN      4096
#define DOUT     4096
#define NE       8
#define RANK     16
#define KEXT     128         // NE*RANK
#define KTOT     4224        // DIN + KEXT
#define SCALING  2.0f

typedef __attribute__((ext_vector_type(8))) short   short8;   // 8 bf16 in 4 VGPRs
typedef __attribute__((ext_vector_type(4))) float   float4v;

__device__ __forceinline__ unsigned short f2bf(float f) {
    union { float f; unsigned int u; } c; c.f = f;
    unsigned int u = c.u;
    u += 0x7FFFu + ((u >> 16) & 1u);          // round-to-nearest-even
    return (unsigned short)(u >> 16);
}

#define GLD_LDS(g, l) __builtin_amdgcn_global_load_lds( \
    (const __attribute__((address_space(1))) void*)(g), \
    (__attribute__((address_space(3))) void*)(l), 16, 0, 0)

// ---------------------------------------------------------------------------
// Prep 1: Wa[o, 0:4096] = bf16(W_base[o, :])   (one float4 per thread)
// ---------------------------------------------------------------------------
__global__ __launch_bounds__(256) void k_prep_w(const float* __restrict__ Wb,
                                                unsigned short* __restrict__ Wa) {
    int idx = blockIdx.x * 256 + threadIdx.x;       // 0 .. 4194303
    const float4* W4 = (const float4*)Wb;
    float4 v = W4[idx];
    int o  = idx >> 10;                             // 4096/4 = 1024 chunks per row
    int kc = idx & 1023;
    ushort4 p;
    p.x = f2bf(v.x); p.y = f2bf(v.y); p.z = f2bf(v.z); p.w = f2bf(v.w);
    *(ushort4*)(Wa + (size_t)o * KTOT + kc * 4) = p;
}

// ---------------------------------------------------------------------------
// Prep 2: Acat[e*16+r, d] = bf16(A[e,r,d])  (pure cast — A is contiguous)
//         Wa[o, 4096+e*16+r] = bf16(B[e,o,r])
// ---------------------------------------------------------------------------
__global__ __launch_bounds__(256) void k_prep_small(const float* __restrict__ A,
                                                    const float* __restrict__ Bm,
                                                    unsigned short* __restrict__ Acat,
                                                    unsigned short* __restrict__ Wa) {
    int tid = blockIdx.x * 256 + threadIdx.x;       // 0 .. 1048575
    if (tid < NE * RANK * DIN) {
        Acat[tid] = f2bf(A[tid]);
    } else {
        int j   = tid - NE * RANK * DIN;            // 0 .. 524287
        int o   = j >> 7;                           // / 128
        int rem = j & 127;                          // e*16 + r
        int e   = rem >> 4;
        int r   = rem & 15;
        Wa[(size_t)o * KTOT + DIN + rem] = f2bf(Bm[(size_t)e * (DOUT * RANK) + o * RANK + r]);
    }
}

// ---------------------------------------------------------------------------
// Router + x cast. One block per token: cast x[t] -> bf16 into xa, compute
// fp32 logits vs W_router (fp32 so top-k matches reference), top-2 softmax,
// write w8[t, e] = weight * SCALING (0 for unselected).
// ---------------------------------------------------------------------------
__global__ __launch_bounds__(256) void k_router(const float* __restrict__ x,
                                                const float* __restrict__ Wr,
                                                unsigned short* __restrict__ xa,
                                                float* __restrict__ w8) {
    int t   = blockIdx.x;
    int tid = threadIdx.x;
    const float4* x4  = (const float4*)(x + (size_t)t * DIN);
    const float4* Wr4 = (const float4*)Wr;
    unsigned short* xrow = xa + (size_t)t * KTOT;

    float p[NE];
#pragma unroll
    for (int e = 0; e < NE; e++) p[e] = 0.f;

#pragma unroll
    for (int j = 0; j < 4; j++) {
        int c = tid + j * 256;                      // chunk 0..1023
        float4 v = x4[c];
        ushort4 b;
        b.x = f2bf(v.x); b.y = f2bf(v.y); b.z = f2bf(v.z); b.w = f2bf(v.w);
        *(ushort4*)(xrow + c * 4) = b;
#pragma unroll
        for (int e = 0; e < NE; e++) {
            float4 wv = Wr4[e * 1024 + c];
            p[e] += v.x * wv.x + v.y * wv.y + v.z * wv.z + v.w * wv.w;
        }
    }
    // wave reduce (64 lanes)
#pragma unroll
    for (int e = 0; e < NE; e++) {
        float v = p[e];
#pragma unroll
        for (int off = 32; off > 0; off >>= 1) v += __shfl_xor(v, off);
        p[e] = v;
    }
    __shared__ float red[4][NE];
    int lane = tid & 63, w = tid >> 6;
    if (lane == 0) {
#pragma unroll
        for (int e = 0; e < NE; e++) red[w][e] = p[e];
    }
    __syncthreads();
    if (tid == 0) {
        float lg[NE];
#pragma unroll
        for (int e = 0; e < NE; e++)
            lg[e] = red[0][e] + red[1][e] + red[2][e] + red[3][e];
        int e0 = 0;
#pragma unroll
        for (int e = 1; e < NE; e++) if (lg[e] > lg[e0]) e0 = e;
        int e1 = -1;
#pragma unroll
        for (int e = 0; e < NE; e++)
            if (e != e0 && (e1 < 0 || lg[e] > lg[e1])) e1 = e;
        float a0 = 1.0f;                            // exp(lg0 - lg0)
        float a1 = __expf(lg[e1] - lg[e0]);
        float inv = 1.0f / (a0 + a1);
        float s0 = a0 * inv * SCALING;
        float s1 = a1 * inv * SCALING;
        float* wrow = w8 + t * NE;
#pragma unroll
        for (int e = 0; e < NE; e++)
            wrow[e] = (e == e0) ? s0 : ((e == e1) ? s1 : 0.f);
    }
}

// ---------------------------------------------------------------------------
// h GEMM: h_all[t, er] = x[t]·A[er] (bf16 MFMA), epilogue applies router
// weight and writes bf16 into xa[t, 4096+er]. M=8192 N=128 K=4096.
// Tile: BM=32, BN=128, BK=32. 256 blocks x 256 threads (4 waves, each 32x32).
// ---------------------------------------------------------------------------
__global__ __launch_bounds__(256) void k_h(unsigned short* xa,
                                           const unsigned short* __restrict__ Acat,
                                           const float* __restrict__ w8) {
    __shared__ unsigned short lds[32 * 32 + 128 * 32];   // 1024 + 4096 ushorts
    int m0  = blockIdx.x * 32;
    int tid = threadIdx.x;
    int l = tid & 63, w = tid >> 6;
    int quad = l >> 4, lr = l & 15;

    float4v acc[2][2] = {};

    for (int k0 = 0; k0 < DIN; k0 += 32) {
        __syncthreads();
        if (w < 2) {                                // x tile: 128 chunks of 16B
            int c = w * 64 + l;
            int row = c >> 2, kc = c & 3;
            GLD_LDS(xa + (size_t)(m0 + row) * KTOT + k0 + kc * 8, lds + c * 8);
        }
#pragma unroll
        for (int it = 0; it < 2; it++) {            // Acat tile: 512 chunks
            int c = it * 256 + w * 64 + l;
            int row = c >> 2, kc = c & 3;
            GLD_LDS(Acat + (size_t)row * DIN + k0 + kc * 8, lds + 1024 + c * 8);
        }
        __syncthreads();

        short8 a[2], b[2];
#pragma unroll
        for (int mi = 0; mi < 2; mi++)
            a[mi] = *(const short8*)(lds + (mi * 16 + lr) * 32 + quad * 8);
#pragma unroll
        for (int ni = 0; ni < 2; ni++)
            b[ni] = *(const short8*)(lds + 1024 + (w * 32 + ni * 16 + lr) * 32 + quad * 8);
#pragma unroll
        for (int mi = 0; mi < 2; mi++)
#pragma unroll
            for (int ni = 0; ni < 2; ni++)
                acc[mi][ni] = __builtin_amdgcn_mfma_f32_16x16x32_bf16(a[mi], b[ni], acc[mi][ni], 0, 0, 0);
    }

#pragma unroll
    for (int mi = 0; mi < 2; mi++)
#pragma unroll
        for (int ni = 0; ni < 2; ni++) {
            int col = w * 32 + ni * 16 + lr;        // 0..127  (er index)
            int e = col >> 4;
#pragma unroll
            for (int i = 0; i < 4; i++) {
                int t = m0 + mi * 16 + quad * 4 + i;
                float v = acc[mi][ni][i] * w8[t * NE + e];
                xa[(size_t)t * KTOT + DIN + col] = f2bf(v);
            }
        }
}

// ---------------------------------------------------------------------------
// Main GEMM: out[t,o] = b_base[o] + sum_k xa[t,k]*Wa[o,k], K=4224.
// m97-style: 128x128 tile, BK=32, 4 waves each 64x64 (4x4 of 16x16x32 MFMA),
// global_load_lds width=16, 2-barrier K-loop.
// ---------------------------------------------------------------------------
__global__ __launch_bounds__(256) void k_main(const unsigned short* __restrict__ xa,
                                              const unsigned short* __restrict__ Wa,
                                              const float* __restrict__ bias,
                                              float* __restrict__ out) {
    __shared__ unsigned short lds[2 * 128 * 32];    // X tile (4096) + W tile (4096)
    int bm = blockIdx.x, bn = blockIdx.y;
    int tid = threadIdx.x;
    int l = tid & 63, w = tid >> 6;
    int quad = l >> 4, lr = l & 15;
    int wm = w >> 1, wn = w & 1;

    const size_t xbase = (size_t)bm * 128 * KTOT;
    const size_t wbase = (size_t)bn * 128 * KTOT;

    float4v acc[4][4] = {};

    for (int k0 = 0; k0 < KTOT; k0 += 32) {
        __syncthreads();
#pragma unroll
        for (int it = 0; it < 2; it++) {
            int c = it * 256 + w * 64 + l;          // 0..511
            int row = c >> 2, kc = c & 3;
            GLD_LDS(xa + xbase + (size_t)row * KTOT + k0 + kc * 8, lds + c * 8);
            GLD_LDS(Wa + wbase + (size_t)row * KTOT + k0 + kc * 8, lds + 4096 + c * 8);
        }
        __syncthreads();

        short8 a[4], b[4];
#pragma unroll
        for (int mi = 0; mi < 4; mi++)
            a[mi] = *(const short8*)(lds + (wm * 64 + mi * 16 + lr) * 32 + quad * 8);
#pragma unroll
        for (int ni = 0; ni < 4; ni++)
            b[ni] = *(const short8*)(lds + 4096 + (wn * 64 + ni * 16 + lr) * 32 + quad * 8);
#pragma unroll
        for (int mi = 0; mi < 4; mi++)
#pragma unroll
            for (int ni = 0; ni < 4; ni++)
                acc[mi][ni] = __builtin_amdgcn_mfma_f32_16x16x32_bf16(a[mi], b[ni], acc[mi][ni], 0, 0, 0);
    }

    int trow0 = bm * 128 + wm * 64;
    int ocol0 = bn * 128 + wn * 64;
#pragma unroll
    for (int ni = 0; ni < 4; ni++) {
        int o = ocol0 + ni * 16 + lr;
        float bb = bias[o];
#pragma unroll
        for (int mi = 0; mi < 4; mi++) {
#pragma unroll
            for (int i = 0; i < 4; i++) {
                int t = trow0 + mi * 16 + quad * 4 + i;
                out[(size_t)t * DOUT + o] = acc[mi][ni][i] + bb;
            }
        }
    }
}

// ---------------------------------------------------------------------------
extern "C" void kernel_launch(void* const* d_in, const int* in_sizes, int n_in,
                              void* d_out, int out_size, void* d_ws, size_t ws_size,
                              hipStream_t stream) {
    const float* x  = (const float*)d_in[0];   // [4,2048,4096]
    const float* Wb = (const float*)d_in[1];   // [4096,4096]
    const float* bb = (const float*)d_in[2];   // [4096]
    const float* Wr = (const float*)d_in[3];   // [8,4096]
    const float* A  = (const float*)d_in[4];   // [8,16,4096]
    const float* Bm = (const float*)d_in[5];   // [8,4096,16]
    float* out = (float*)d_out;

    char* ws = (char*)d_ws;
    unsigned short* xa   = (unsigned short*)(ws);                       // 8192*4224*2 = 69,206,016 B
    unsigned short* Wa   = (unsigned short*)(ws + 69206016);            // 4096*4224*2 = 34,603,008 B
    unsigned short* Acat = (unsigned short*)(ws + 69206016 + 34603008); // 128*4096*2  =  1,048,576 B
    float*          w8   = (float*)(ws + 69206016 + 34603008 + 1048576);// 8192*8*4    =    262,144 B
    // total: 105,119,744 B

    k_prep_w    <<<dim3(16384), dim3(256), 0, stream>>>(Wb, Wa);
    k_prep_small<<<dim3(4096),  dim3(256), 0, stream>>>(A, Bm, Acat, Wa);
    k_router    <<<dim3(8192),  dim3(256), 0, stream>>>(x, Wr, xa, w8);
    k_h         <<<dim3(256),   dim3(256), 0, stream>>>(xa, Acat, w8);
    k_main      <<<dim3(64, 32), dim3(256), 0, stream>>>(xa, Wa, bb, out);
}

// Round 2
// 667.849 us; speedup vs baseline: 1.0599x; 1.0599x over previous
//
#include <hip/hip_runtime.h>
#include <hip/hip_bf16.h>
#include <stdint.h>

// Problem constants (MixtureOfLinear: B=4,S=2048,D=4096, E=8, top-2, rank 16)
#define T_TOKENS 8192
#define DIN      4096
#define DOUT     4096
#define NE       8
#define RANK     16
#define KEXT     128         // NE*RANK
#define KTOT     4224        // DIN + KEXT
#define SCALING  2.0f

typedef __attribute__((ext_vector_type(8))) short   short8;   // 8 bf16 in 4 VGPRs
typedef __attribute__((ext_vector_type(4))) float   float4v;

__device__ __forceinline__ unsigned short f2bf(float f) {
    union { float f; unsigned int u; } c; c.f = f;
    unsigned int u = c.u;
    u += 0x7FFFu + ((u >> 16) & 1u);          // round-to-nearest-even
    return (unsigned short)(u >> 16);
}

#define GLD_LDS(g, l) __builtin_amdgcn_global_load_lds( \
    (const __attribute__((address_space(1))) void*)(g), \
    (__attribute__((address_space(3))) void*)(l), 16, 0, 0)

// ---------------------------------------------------------------------------
// Prep (merged): blocks [0,16384): Wa[o,0:4096] = bf16(W_base)
//                blocks [16384,20480): Acat cast + Wa B-extension pack
// ---------------------------------------------------------------------------
__global__ __launch_bounds__(256) void k_prep(const float* __restrict__ Wb,
                                              const float* __restrict__ A,
                                              const float* __restrict__ Bm,
                                              unsigned short* __restrict__ Wa,
                                              unsigned short* __restrict__ Acat) {
    int b = blockIdx.x;
    if (b < 16384) {
        int idx = b * 256 + threadIdx.x;            // 0 .. 4194303
        const float4* W4 = (const float4*)Wb;
        float4 v = W4[idx];
        int o  = idx >> 10;
        int kc = idx & 1023;
        ushort4 p;
        p.x = f2bf(v.x); p.y = f2bf(v.y); p.z = f2bf(v.z); p.w = f2bf(v.w);
        *(ushort4*)(Wa + (size_t)o * KTOT + kc * 4) = p;
    } else {
        int tid = (b - 16384) * 256 + threadIdx.x;  // 0 .. 1048575
        if (tid < NE * RANK * DIN) {
            Acat[tid] = f2bf(A[tid]);
        } else {
            int j   = tid - NE * RANK * DIN;        // 0 .. 524287
            int o   = j >> 7;
            int rem = j & 127;                      // e*16 + r
            int e   = rem >> 4;
            int r   = rem & 15;
            Wa[(size_t)o * KTOT + DIN + rem] = f2bf(Bm[(size_t)e * (DOUT * RANK) + o * RANK + r]);
        }
    }
}

// ---------------------------------------------------------------------------
// Fused front-end: per 32-token block — read x once (fp32), cast->bf16 into
// xa[:,0:4096] + LDS, accumulate fp32 router logits, MFMA h = x·Acat^T
// (BK=128), then top-2 softmax and scaled-h write into xa[:,4096:4224].
// ---------------------------------------------------------------------------
#define FBM 32
#define FBK 128
__global__ __launch_bounds__(256) void k_front(const float* __restrict__ x,
                                               const float* __restrict__ Wr,
                                               const unsigned short* __restrict__ Acat,
                                               unsigned short* __restrict__ xa) {
    __shared__ unsigned short lds_x[FBM * 136];     // padded stride (+8) -> conflict-free
    __shared__ unsigned short lds_a[128 * FBK];     // GLD target: unpadded, xor-swizzled
    __shared__ float lds_wr[NE * FBK];              // router weight chunk (fp32)
    __shared__ float lds_red[FBM][8][NE];           // router partials
    __shared__ float lds_wsc[FBM][NE];              // final scaled router weights

    int m0  = blockIdx.x * FBM;
    int tid = threadIdx.x;
    int t_local = tid >> 3;                         // 0..31
    int slice   = tid & 7;                          // 0..7 (16 cols each)
    int l = tid & 63, w = tid >> 6;
    int quad = l >> 4, lr = l & 15;

    const float* xrow = x + (size_t)(m0 + t_local) * DIN;
    unsigned short* xarow = xa + (size_t)(m0 + t_local) * KTOT;

    float racc[NE];
#pragma unroll
    for (int e = 0; e < NE; e++) racc[e] = 0.f;
    float4v acc[2][2] = {};

    for (int k0 = 0; k0 < DIN; k0 += FBK) {
        __syncthreads();                            // LDS reads of prev iter done
        // ---- x: load fp32, cast, write to xa global + LDS tile ----
        float4 xv[4];
#pragma unroll
        for (int j = 0; j < 4; j++)
            xv[j] = *(const float4*)(xrow + k0 + slice * 16 + j * 4);
        short8 pk0, pk1;
        pk0[0] = f2bf(xv[0].x); pk0[1] = f2bf(xv[0].y); pk0[2] = f2bf(xv[0].z); pk0[3] = f2bf(xv[0].w);
        pk0[4] = f2bf(xv[1].x); pk0[5] = f2bf(xv[1].y); pk0[6] = f2bf(xv[1].z); pk0[7] = f2bf(xv[1].w);
        pk1[0] = f2bf(xv[2].x); pk1[1] = f2bf(xv[2].y); pk1[2] = f2bf(xv[2].z); pk1[3] = f2bf(xv[2].w);
        pk1[4] = f2bf(xv[3].x); pk1[5] = f2bf(xv[3].y); pk1[6] = f2bf(xv[3].z); pk1[7] = f2bf(xv[3].w);
        *(short8*)(xarow + k0 + slice * 16)     = pk0;
        *(short8*)(xarow + k0 + slice * 16 + 8) = pk1;
        *(short8*)&lds_x[t_local * 136 + slice * 16]     = pk0;
        *(short8*)&lds_x[t_local * 136 + slice * 16 + 8] = pk1;
        // ---- Wr chunk -> LDS (fp32) ----
        {
            int e = tid >> 5;                       // 0..7
            int c = (tid & 31) * 4;                 // 0..124
            *(float4*)&lds_wr[e * FBK + c] = *(const float4*)(Wr + (size_t)e * DIN + k0 + c);
        }
        // ---- Acat tile via global_load_lds, xor-swizzled on the GLOBAL side ----
#pragma unroll
        for (int it = 0; it < 8; it++) {
            int c = it * 256 + tid;                 // 0..2047
            int row = c >> 4, kc = c & 15;
            int p = (row ^ (row >> 2)) & 15;
            GLD_LDS(Acat + (size_t)row * DIN + k0 + (kc ^ p) * 8, lds_a + c * 8);
        }
        __syncthreads();
        // ---- router FMA (fp32) ----
#pragma unroll
        for (int e = 0; e < NE; e++) {
#pragma unroll
            for (int j = 0; j < 4; j++) {
                float4 wv = *(const float4*)&lds_wr[e * FBK + slice * 16 + j * 4];
                racc[e] += xv[j].x * wv.x + xv[j].y * wv.y + xv[j].z * wv.z + xv[j].w * wv.w;
            }
        }
        // ---- MFMA h accumulate ----
#pragma unroll
        for (int kk = 0; kk < 4; kk++) {
            short8 a[2], b[2];
#pragma unroll
            for (int mi = 0; mi < 2; mi++)
                a[mi] = *(const short8*)&lds_x[(mi * 16 + lr) * 136 + kk * 32 + quad * 8];
#pragma unroll
            for (int ni = 0; ni < 2; ni++) {
                int rown = w * 32 + ni * 16 + lr;
                int pn = (rown ^ (rown >> 2)) & 15;
                b[ni] = *(const short8*)&lds_a[rown * FBK + ((kk * 4 + quad) ^ pn) * 8];
            }
#pragma unroll
            for (int mi = 0; mi < 2; mi++)
#pragma unroll
                for (int ni = 0; ni < 2; ni++)
                    acc[mi][ni] = __builtin_amdgcn_mfma_f32_16x16x32_bf16(a[mi], b[ni], acc[mi][ni], 0, 0, 0);
        }
    }

    // ---- router reduce + top-2 softmax ----
#pragma unroll
    for (int e = 0; e < NE; e++) lds_red[t_local][slice][e] = racc[e];
    __syncthreads();
    if (tid < FBM) {
        float lg[NE];
#pragma unroll
        for (int e = 0; e < NE; e++) {
            float s = 0.f;
#pragma unroll
            for (int j = 0; j < 8; j++) s += lds_red[tid][j][e];
            lg[e] = s;
        }
        int e0 = 0;
#pragma unroll
        for (int e = 1; e < NE; e++) if (lg[e] > lg[e0]) e0 = e;
        int e1 = -1;
#pragma unroll
        for (int e = 0; e < NE; e++)
            if (e != e0 && (e1 < 0 || lg[e] > lg[e1])) e1 = e;
        float a1 = __expf(lg[e1] - lg[e0]);
        float inv = 1.0f / (1.0f + a1);
#pragma unroll
        for (int e = 0; e < NE; e++)
            lds_wsc[tid][e] = (e == e0) ? inv * SCALING : ((e == e1) ? a1 * inv * SCALING : 0.f);
    }
    __syncthreads();

    // ---- epilogue: scale h by router weight, write bf16 K-extension ----
#pragma unroll
    for (int mi = 0; mi < 2; mi++)
#pragma unroll
        for (int ni = 0; ni < 2; ni++) {
            int col = w * 32 + ni * 16 + lr;        // er index 0..127
            int e = col >> 4;
#pragma unroll
            for (int i = 0; i < 4; i++) {
                int t = mi * 16 + quad * 4 + i;     // local token
                float v = acc[mi][ni][i] * lds_wsc[t][e];
                xa[(size_t)(m0 + t) * KTOT + DIN + col] = f2bf(v);
            }
        }
}

// ---------------------------------------------------------------------------
// Main GEMM: out[t,o] = b_base[o] + xa[t,:]·Wa[o,:], K=4224. m97 structure +
// xor chunk swizzle (global-source side) to break LDS bank conflicts.
// ---------------------------------------------------------------------------
__global__ __launch_bounds__(256) void k_main(const unsigned short* __restrict__ xa,
                                              const unsigned short* __restrict__ Wa,
                                              const float* __restrict__ bias,
                                              float* __restrict__ out) {
    __shared__ unsigned short lds[2 * 128 * 32];    // X tile (4096) + W tile (4096)
    int bm = blockIdx.x, bn = blockIdx.y;
    int tid = threadIdx.x;
    int l = tid & 63, w = tid >> 6;
    int quad = l >> 4, lr = l & 15;
    int wm = w >> 1, wn = w & 1;

    const size_t xbase = (size_t)bm * 128 * KTOT;
    const size_t wbase = (size_t)bn * 128 * KTOT;

    // swizzle constants (thread-invariant in K-loop)
    int pa = (lr ^ (lr >> 2)) & 3;                  // p(row) for row ≡ lr (mod 16)
    int sa = (quad ^ pa) * 8;                       // slot offset in ushorts

    float4v acc[4][4] = {};

    for (int k0 = 0; k0 < KTOT; k0 += 32) {
        __syncthreads();
#pragma unroll
        for (int it = 0; it < 2; it++) {
            int c = it * 256 + tid;                 // 0..511
            int row = c >> 2, kc = c & 3;
            int p = (row ^ (row >> 2)) & 3;
            int kcs = kc ^ p;
            GLD_LDS(xa + xbase + (size_t)row * KTOT + k0 + kcs * 8, lds + c * 8);
            GLD_LDS(Wa + wbase + (size_t)row * KTOT + k0 + kcs * 8, lds + 4096 + c * 8);
        }
        __syncthreads();

        short8 a[4], b[4];
#pragma unroll
        for (int mi = 0; mi < 4; mi++)
            a[mi] = *(const short8*)(lds + (wm * 64 + mi * 16 + lr) * 32 + sa);
#pragma unroll
        for (int ni = 0; ni < 4; ni++)
            b[ni] = *(const short8*)(lds + 4096 + (wn * 64 + ni * 16 + lr) * 32 + sa);
#pragma unroll
        for (int mi = 0; mi < 4; mi++)
#pragma unroll
            for (int ni = 0; ni < 4; ni++)
                acc[mi][ni] = __builtin_amdgcn_mfma_f32_16x16x32_bf16(a[mi], b[ni], acc[mi][ni], 0, 0, 0);
    }

    int trow0 = bm * 128 + wm * 64;
    int ocol0 = bn * 128 + wn * 64;
#pragma unroll
    for (int ni = 0; ni < 4; ni++) {
        int o = ocol0 + ni * 16 + lr;
        float bb = bias[o];
#pragma unroll
        for (int mi = 0; mi < 4; mi++) {
#pragma unroll
            for (int i = 0; i < 4; i++) {
                int t = trow0 + mi * 16 + quad * 4 + i;
                out[(size_t)t * DOUT + o] = acc[mi][ni][i] + bb;
            }
        }
    }
}

// ---------------------------------------------------------------------------
extern "C" void kernel_launch(void* const* d_in, const int* in_sizes, int n_in,
                              void* d_out, int out_size, void* d_ws, size_t ws_size,
                              hipStream_t stream) {
    const float* x  = (const float*)d_in[0];   // [4,2048,4096]
    const float* Wb = (const float*)d_in[1];   // [4096,4096]
    const float* bb = (const float*)d_in[2];   // [4096]
    const float* Wr = (const float*)d_in[3];   // [8,4096]
    const float* A  = (const float*)d_in[4];   // [8,16,4096]
    const float* Bm = (const float*)d_in[5];   // [8,4096,16]
    float* out = (float*)d_out;

    char* ws = (char*)d_ws;
    unsigned short* xa   = (unsigned short*)(ws);                       // 8192*4224*2 = 69,206,016 B
    unsigned short* Wa   = (unsigned short*)(ws + 69206016);            // 4096*4224*2 = 34,603,008 B
    unsigned short* Acat = (unsigned short*)(ws + 69206016 + 34603008); // 128*4096*2  =  1,048,576 B
    // total: 104,857,600 B

    k_prep <<<dim3(20480), dim3(256), 0, stream>>>(Wb, A, Bm, Wa, Acat);
    k_front<<<dim3(256),   dim3(256), 0, stream>>>(x, Wr, Acat, xa);
    k_main <<<dim3(64, 32), dim3(256), 0, stream>>>(xa, Wa, bb, out);
}

// Round 3
// 629.145 us; speedup vs baseline: 1.1251x; 1.0615x over previous
//
#include <hip/hip_runtime.h>
#include <hip/hip_bf16.h>
#include <stdint.h>

// Problem constants (MixtureOfLinear: B=4,S=2048,D=4096, E=8, top-2, rank 16)
#define T_TOKENS 8192
#define DIN      4096
#define DOUT     4096
#define NE       8
#define RANK     16
#define KEXT     128         // NE*RANK
#define KTOT     4224        // DIN + KEXT
#define SCALING  2.0f

typedef __attribute__((ext_vector_type(8))) short   short8;   // 8 bf16 in 4 VGPRs
typedef __attribute__((ext_vector_type(4))) float   float4v;

__device__ __forceinline__ unsigned short f2bf(float f) {
    union { float f; unsigned int u; } c; c.f = f;
    unsigned int u = c.u;
    u += 0x7FFFu + ((u >> 16) & 1u);          // round-to-nearest-even
    return (unsigned short)(u >> 16);
}

#define GLD_LDS(g, l) __builtin_amdgcn_global_load_lds( \
    (const __attribute__((address_space(1))) void*)(g), \
    (__attribute__((address_space(3))) void*)(l), 16, 0, 0)

// ---------------------------------------------------------------------------
// Kernel 1 (merged front-end, all parts independent):
//  blocks [0,2048):      x cast -> xa[:,0:4096] bf16 + fp32 router -> w8
//                        (one token per wave, 4 tokens per block)
//  blocks [2048,18432):  Wa[o,0:4096] = bf16(W_base)
//  blocks [18432,22528): Acat cast + Wa[:,4096:] = bf16(B) pack
// ---------------------------------------------------------------------------
__global__ __launch_bounds__(256) void k_front(const float* __restrict__ x,
                                               const float* __restrict__ Wr,
                                               const float* __restrict__ Wb,
                                               const float* __restrict__ A,
                                               const float* __restrict__ Bm,
                                               unsigned short* __restrict__ xa,
                                               unsigned short* __restrict__ Wa,
                                               unsigned short* __restrict__ Acat,
                                               float* __restrict__ w8) {
    __shared__ float lds_wr[8 * 1024];              // 8 experts x 1024 floats (32 KB)
    int b = blockIdx.x;
    int tid = threadIdx.x;

    if (b < 2048) {
        // ---- cast + router: token t handled by wave w ----
        int l = tid & 63, w = tid >> 6;
        int t = b * 4 + w;
        const float4* x4 = (const float4*)x;
        const float4* Wr4 = (const float4*)Wr;
        unsigned short* xarow = xa + (size_t)t * KTOT;

        float racc[NE];
#pragma unroll
        for (int e = 0; e < NE; e++) racc[e] = 0.f;

        for (int ci = 0; ci < 4; ci++) {            // 1024 floats per iter
            __syncthreads();
#pragma unroll
            for (int jj = 0; jj < 8; jj++) {        // stage Wr chunk (fp32)
                int f = jj * 256 + tid;             // float4 index 0..2047
                int e = f >> 8, col = f & 255;
                *(float4*)&lds_wr[f * 4] = Wr4[e * 1024 + ci * 256 + col];
            }
            __syncthreads();
            float4 xv[4];
#pragma unroll
            for (int j = 0; j < 4; j++)
                xv[j] = x4[(size_t)t * 1024 + ci * 256 + j * 64 + l];
#pragma unroll
            for (int j = 0; j < 4; j++) {
                ushort4 p;
                p.x = f2bf(xv[j].x); p.y = f2bf(xv[j].y);
                p.z = f2bf(xv[j].z); p.w = f2bf(xv[j].w);
                *(ushort4*)(xarow + (ci * 256 + j * 64 + l) * 4) = p;
            }
#pragma unroll
            for (int e = 0; e < NE; e++) {
#pragma unroll
                for (int j = 0; j < 4; j++) {
                    float4 wv = *(const float4*)&lds_wr[(e * 256 + j * 64 + l) * 4];
                    racc[e] += xv[j].x * wv.x + xv[j].y * wv.y + xv[j].z * wv.z + xv[j].w * wv.w;
                }
            }
        }
        // wave butterfly reduce (64 lanes)
#pragma unroll
        for (int e = 0; e < NE; e++) {
            float v = racc[e];
#pragma unroll
            for (int off = 32; off > 0; off >>= 1) v += __shfl_xor(v, off);
            racc[e] = v;
        }
        if (l == 0) {
            int e0 = 0;
#pragma unroll
            for (int e = 1; e < NE; e++) if (racc[e] > racc[e0]) e0 = e;
            int e1 = -1;
#pragma unroll
            for (int e = 0; e < NE; e++)
                if (e != e0 && (e1 < 0 || racc[e] > racc[e1])) e1 = e;
            float a1 = __expf(racc[e1] - racc[e0]);
            float inv = 1.0f / (1.0f + a1);
            float* wrow = w8 + t * NE;
#pragma unroll
            for (int e = 0; e < NE; e++)
                wrow[e] = (e == e0) ? inv * SCALING : ((e == e1) ? a1 * inv * SCALING : 0.f);
        }
    } else if (b < 18432) {
        // ---- W_base cast ----
        int idx = (b - 2048) * 256 + tid;           // 0 .. 4194303
        float4 v = ((const float4*)Wb)[idx];
        int o  = idx >> 10;
        int kc = idx & 1023;
        ushort4 p;
        p.x = f2bf(v.x); p.y = f2bf(v.y); p.z = f2bf(v.z); p.w = f2bf(v.w);
        *(ushort4*)(Wa + (size_t)o * KTOT + kc * 4) = p;
    } else {
        // ---- A cast + B pack ----
        int tid2 = (b - 18432) * 256 + tid;         // 0 .. 1048575
        if (tid2 < NE * RANK * DIN) {
            Acat[tid2] = f2bf(A[tid2]);
        } else {
            int j   = tid2 - NE * RANK * DIN;       // 0 .. 524287
            int o   = j >> 7;
            int rem = j & 127;                      // e*16 + r
            int e   = rem >> 4;
            int r   = rem & 15;
            Wa[(size_t)o * KTOT + DIN + rem] = f2bf(Bm[(size_t)e * (DOUT * RANK) + o * RANK + r]);
        }
    }
}

// ---------------------------------------------------------------------------
// k_h: h[t,er] = xa_bf16[t,:4096] · Acat[er,:], scaled by router weight,
// written into xa[t, 4096+er]. M=8192 N=128 K=4096. BM=32, BK=128, 32 iters.
// LDS slots permuted via the GLOBAL source address (legal under
// global_load_lds): chunk (row,kc) lives at slot row*16 + (kc ^ (row&15)),
// making every fragment read a permutation of consecutive 16B chunks
// (conflict-free).
// ---------------------------------------------------------------------------
__global__ __launch_bounds__(256) void k_h(unsigned short* __restrict__ xa,
                                           const unsigned short* __restrict__ Acat,
                                           const float* __restrict__ w8) {
    __shared__ unsigned short lds_x[32 * 128];      // 8 KB
    __shared__ unsigned short lds_a[128 * 128];     // 32 KB
    int m0  = blockIdx.x * 32;
    int tid = threadIdx.x;
    int l = tid & 63, w = tid >> 6;
    int quad = l >> 4, lr = l & 15;

    float4v acc[2][2] = {};                         // [mi][ni]

    for (int k0 = 0; k0 < DIN; k0 += 128) {
        __syncthreads();
#pragma unroll
        for (int it = 0; it < 2; it++) {            // x tile: 512 chunks
            int c = it * 256 + tid;
            int row = c >> 4, s = c & 15;
            int kc = s ^ (row & 15);
            GLD_LDS(xa + (size_t)(m0 + row) * KTOT + k0 + kc * 8, lds_x + c * 8);
        }
#pragma unroll
        for (int it = 0; it < 8; it++) {            // A tile: 2048 chunks
            int c = it * 256 + tid;
            int row = c >> 4, s = c & 15;
            int kc = s ^ (row & 15);
            GLD_LDS(Acat + (size_t)row * DIN + k0 + kc * 8, lds_a + c * 8);
        }
        __syncthreads();
#pragma unroll
        for (int kk = 0; kk < 4; kk++) {
            int kc = kk * 4 + quad;
            short8 a[2], bfr[2];
#pragma unroll
            for (int mi = 0; mi < 2; mi++) {
                int row = mi * 16 + lr;
                a[mi] = *(const short8*)&lds_x[row * 128 + ((kc ^ lr) * 8)];
            }
#pragma unroll
            for (int ni = 0; ni < 2; ni++) {
                int row = w * 32 + ni * 16 + lr;
                bfr[ni] = *(const short8*)&lds_a[row * 128 + ((kc ^ lr) * 8)];
            }
#pragma unroll
            for (int mi = 0; mi < 2; mi++)
#pragma unroll
                for (int ni = 0; ni < 2; ni++)
                    acc[mi][ni] = __builtin_amdgcn_mfma_f32_16x16x32_bf16(a[mi], bfr[ni], acc[mi][ni], 0, 0, 0);
        }
    }

#pragma unroll
    for (int mi = 0; mi < 2; mi++)
#pragma unroll
        for (int ni = 0; ni < 2; ni++) {
            int col = w * 32 + ni * 16 + lr;        // er index 0..127
            int e = col >> 4;
#pragma unroll
            for (int i = 0; i < 4; i++) {
                int t = m0 + mi * 16 + quad * 4 + i;
                float v = acc[mi][ni][i] * w8[t * NE + e];
                xa[(size_t)t * KTOT + DIN + col] = f2bf(v);
            }
        }
}

// ---------------------------------------------------------------------------
// Main GEMM: out[t,o] = b_base[o] + xa[t,:]·Wa[o,:], K=4224. m97 structure
// (128x128 tile, BK=32, global_load_lds width=16, 2-barrier K-loop).
// ---------------------------------------------------------------------------
__global__ __launch_bounds__(256) void k_main(const unsigned short* __restrict__ xa,
                                              const unsigned short* __restrict__ Wa,
                                              const float* __restrict__ bias,
                                              float* __restrict__ out) {
    __shared__ unsigned short lds[2 * 128 * 32];    // X tile (4096) + W tile (4096)
    int bm = blockIdx.x, bn = blockIdx.y;
    int tid = threadIdx.x;
    int l = tid & 63, w = tid >> 6;
    int quad = l >> 4, lr = l & 15;
    int wm = w >> 1, wn = w & 1;

    const size_t xbase = (size_t)bm * 128 * KTOT;
    const size_t wbase = (size_t)bn * 128 * KTOT;

    float4v acc[4][4] = {};

    for (int k0 = 0; k0 < KTOT; k0 += 32) {
        __syncthreads();
#pragma unroll
        for (int it = 0; it < 2; it++) {
            int c = it * 256 + tid;                 // 0..511
            int row = c >> 2, kc = c & 3;
            GLD_LDS(xa + xbase + (size_t)row * KTOT + k0 + kc * 8, lds + c * 8);
            GLD_LDS(Wa + wbase + (size_t)row * KTOT + k0 + kc * 8, lds + 4096 + c * 8);
        }
        __syncthreads();

        short8 a[4], b[4];
#pragma unroll
        for (int mi = 0; mi < 4; mi++)
            a[mi] = *(const short8*)(lds + (wm * 64 + mi * 16 + lr) * 32 + quad * 8);
#pragma unroll
        for (int ni = 0; ni < 4; ni++)
            b[ni] = *(const short8*)(lds + 4096 + (wn * 64 + ni * 16 + lr) * 32 + quad * 8);
#pragma unroll
        for (int mi = 0; mi < 4; mi++)
#pragma unroll
            for (int ni = 0; ni < 4; ni++)
                acc[mi][ni] = __builtin_amdgcn_mfma_f32_16x16x32_bf16(a[mi], b[ni], acc[mi][ni], 0, 0, 0);
    }

    int trow0 = bm * 128 + wm * 64;
    int ocol0 = bn * 128 + wn * 64;
#pragma unroll
    for (int ni = 0; ni < 4; ni++) {
        int o = ocol0 + ni * 16 + lr;
        float bb = bias[o];
#pragma unroll
        for (int mi = 0; mi < 4; mi++) {
#pragma unroll
            for (int i = 0; i < 4; i++) {
                int t = trow0 + mi * 16 + quad * 4 + i;
                out[(size_t)t * DOUT + o] = acc[mi][ni][i] + bb;
            }
        }
    }
}

// ---------------------------------------------------------------------------
extern "C" void kernel_launch(void* const* d_in, const int* in_sizes, int n_in,
                              void* d_out, int out_size, void* d_ws, size_t ws_size,
                              hipStream_t stream) {
    const float* x  = (const float*)d_in[0];   // [4,2048,4096]
    const float* Wb = (const float*)d_in[1];   // [4096,4096]
    const float* bb = (const float*)d_in[2];   // [4096]
    const float* Wr = (const float*)d_in[3];   // [8,4096]
    const float* A  = (const float*)d_in[4];   // [8,16,4096]
    const float* Bm = (const float*)d_in[5];   // [8,4096,16]
    float* out = (float*)d_out;

    char* ws = (char*)d_ws;
    unsigned short* xa   = (unsigned short*)(ws);                       // 8192*4224*2 = 69,206,016 B
    unsigned short* Wa   = (unsigned short*)(ws + 69206016);            // 4096*4224*2 = 34,603,008 B
    unsigned short* Acat = (unsigned short*)(ws + 69206016 + 34603008); // 128*4096*2  =  1,048,576 B
    float*          w8   = (float*)(ws + 69206016 + 34603008 + 1048576);// 8192*8*4    =    262,144 B
    // total: 105,119,744 B

    k_front<<<dim3(22528), dim3(256), 0, stream>>>(x, Wr, Wb, A, Bm, xa, Wa, Acat, w8);
    k_h    <<<dim3(256),   dim3(256), 0, stream>>>(xa, Acat, w8);
    k_main <<<dim3(64, 32), dim3(256), 0, stream>>>(xa, Wa, bb, out);
}